// Round 5
// baseline (105.544 us; speedup 1.0000x reference)
//
#include <hip/hip_runtime.h>

// Problem constants (fixed by setup_inputs): B=4, T=28, N=1024, D=3
constexpr int Bc = 4;
constexpr int Tc = 28;
constexpr int Nc = 1024;
constexpr int Dc = 3;
constexpr int BT = Bc * Tc;       // 112

// ws layout, ALL slots written before read -> no memset needed:
//   packed [112*1024] float4  : [x,y,z,||t||^2] per target   (1.75 MB)
//   partial[224]      float   : per-block weighted sl1 sums
//   psum   [112*3]    float   : per-bt pred-coordinate sums
//   tsum   [112*3]    float   : per-bt target-coordinate sums
constexpr size_t WS_PACKED_F4 = 0;                    // float4 units
constexpr size_t WS_PARTIAL   = (size_t)BT * Nc * 4;  // float units from here
constexpr size_t WS_PSUM      = WS_PARTIAL + 224;
constexpr size_t WS_TSUM      = WS_PSUM + BT * 3;

__device__ __forceinline__ float sl1(float d) {
    d = fabsf(d);
    return d < 1.0f ? 0.5f * d * d : d - 0.5f;
}

// ---------------------------------------------------------------------------
// Prep: 112 blocks (one per bt). Packs targets as [x,y,z,||t||^2] for the hot
// kernel (so tn is never recomputed per-lane), and computes per-bt centroid
// partial sums for BOTH inputs (single read of each; removes 6 of 7 block
// reductions from the hot kernel).
// ---------------------------------------------------------------------------
__global__ __launch_bounds__(256) void prep_kernel(
    const float* __restrict__ X, const float* __restrict__ Tg,
    float4* __restrict__ packed, float* __restrict__ sums)
{
    __shared__ float sred[4][8];
    const int bt  = blockIdx.x;
    const int tid = threadIdx.x;

    const float4* tg4 = (const float4*)(Tg + (size_t)bt * (Nc * Dc));
    const float4 r0 = tg4[3 * tid + 0];
    const float4 r1 = tg4[3 * tid + 1];
    const float4 r2 = tg4[3 * tid + 2];
    float4* pk = packed + (size_t)bt * Nc;
    pk[4 * tid + 0] = make_float4(r0.x, r0.y, r0.z, fmaf(r0.x, r0.x, fmaf(r0.y, r0.y, r0.z * r0.z)));
    pk[4 * tid + 1] = make_float4(r0.w, r1.x, r1.y, fmaf(r0.w, r0.w, fmaf(r1.x, r1.x, r1.y * r1.y)));
    pk[4 * tid + 2] = make_float4(r1.z, r1.w, r2.x, fmaf(r1.z, r1.z, fmaf(r1.w, r1.w, r2.x * r2.x)));
    pk[4 * tid + 3] = make_float4(r2.y, r2.z, r2.w, fmaf(r2.y, r2.y, fmaf(r2.z, r2.z, r2.w * r2.w)));

    const float4* x4 = (const float4*)(X + (size_t)bt * (Nc * Dc));
    const float4 a0 = x4[3 * tid + 0];
    const float4 a1 = x4[3 * tid + 1];
    const float4 a2 = x4[3 * tid + 2];

    float vals[6] = {
        a0.x + a0.w + a1.z + a2.y,   // pred sx
        a0.y + a1.x + a1.w + a2.z,   // pred sy
        a0.z + a1.y + a2.x + a2.w,   // pred sz
        r0.x + r0.w + r1.z + r2.y,   // tgt  sx
        r0.y + r1.x + r1.w + r2.z,   // tgt  sy
        r0.z + r1.y + r2.x + r2.w    // tgt  sz
    };
    const int lane = tid & 63, wid = tid >> 6;
    #pragma unroll
    for (int k = 0; k < 6; ++k) {
        float v = vals[k];
        #pragma unroll
        for (int off = 32; off; off >>= 1) v += __shfl_down(v, off, 64);
        if (lane == 0) sred[wid][k] = v;
    }
    __syncthreads();
    if (tid == 0) {
        #pragma unroll
        for (int k = 0; k < 3; ++k) {
            sums[WS_PSUM - WS_PARTIAL + bt * 3 + k] = sred[0][k] + sred[1][k] + sred[2][k] + sred[3][k];
            sums[WS_TSUM - WS_PARTIAL + bt * 3 + k] = sred[0][k + 3] + sred[1][k + 3] + sred[2][k + 3] + sred[3][k + 3];
        }
    }
}

// ---------------------------------------------------------------------------
// Chamfer: 224 blocks = 112 bt x 2 pred-halves, 256 thr, 2 preds/thread.
// NO LDS in the hot loop (R4 post-mortem: per-CU LDS pipe at ~12 cyc/b128 was
// the floor). Targets are read with a wave-UNIFORM index from a packed global
// array: either SGPR-ized (s_load, scalar pipe) or a 16B coalesced broadcast
// that hits L1 (16 KiB working set < 32 KiB L1). PF=8 register double-buffer
// hides the load latency at 1 wave/SIMD.
// v = tn - 2 p.t is argmin-equivalent to ||p-t||^2 (monotone per-pred shift);
// strict < keeps the first minimum -> matches jnp.argmin tie-break.
// ---------------------------------------------------------------------------
__global__ __launch_bounds__(256) void chamfer_kernel(
    const float* __restrict__ X, const float4* __restrict__ packed,
    const float* __restrict__ W, float* __restrict__ partial)
{
    __shared__ float sred[4];
    const int bt  = blockIdx.x >> 1;
    const int ph  = blockIdx.x & 1;
    const int tid = threadIdx.x;

    const float* xb = X + (size_t)bt * (Nc * Dc);
    const int n0 = ph * 512 + tid;
    const int n1 = n0 + 256;
    const float pAx = xb[n0 * 3 + 0], pAy = xb[n0 * 3 + 1], pAz = xb[n0 * 3 + 2];
    const float pBx = xb[n1 * 3 + 0], pBy = xb[n1 * 3 + 1], pBz = xb[n1 * 3 + 2];

    const float cA0 = -2.0f * pAx, cA1 = -2.0f * pAy, cA2 = -2.0f * pAz;
    const float cB0 = -2.0f * pBx, cB1 = -2.0f * pBy, cB2 = -2.0f * pBz;

    const float4* __restrict__ pk = packed + (size_t)bt * Nc;

    float bestA = 3.4e38f, bestB = 3.4e38f;
    int iA = 0, iB = 0;

    constexpr int PF = 8;           // targets per pipeline stage
    float4 bufA[PF], bufB[PF];

    #pragma unroll
    for (int j = 0; j < PF; ++j) bufA[j] = pk[j];

    for (int m0 = 0; m0 < Nc; m0 += 2 * PF) {
        #pragma unroll
        for (int j = 0; j < PF; ++j) bufB[j] = pk[m0 + PF + j];
        #pragma unroll
        for (int j = 0; j < PF; ++j) {
            const float4 t = bufA[j];
            const int m = m0 + j;
            float vA = fmaf(cA0, t.x, fmaf(cA1, t.y, fmaf(cA2, t.z, t.w)));
            float vB = fmaf(cB0, t.x, fmaf(cB1, t.y, fmaf(cB2, t.z, t.w)));
            bool ca = vA < bestA; bestA = ca ? vA : bestA; iA = ca ? m : iA;
            bool cb = vB < bestB; bestB = cb ? vB : bestB; iB = cb ? m : iB;
        }
        #pragma unroll
        for (int j = 0; j < PF; ++j) bufA[j] = pk[(m0 + 2 * PF + j) & (Nc - 1)];
        #pragma unroll
        for (int j = 0; j < PF; ++j) {
            const float4 t = bufB[j];
            const int m = m0 + PF + j;
            float vA = fmaf(cA0, t.x, fmaf(cA1, t.y, fmaf(cA2, t.z, t.w)));
            float vB = fmaf(cB0, t.x, fmaf(cB1, t.y, fmaf(cB2, t.z, t.w)));
            bool ca = vA < bestA; bestA = ca ? vA : bestA; iA = ca ? m : iA;
            bool cb = vB < bestB; bestB = cb ? vB : bestB; iB = cb ? m : iB;
        }
    }

    // epilogue: gather winners (divergent, one-time, L1/L2-resident)
    const float4 tA = pk[iA];
    const float4 tB = pk[iB];
    float s = sl1(pAx - tA.x) + sl1(pAy - tA.y) + sl1(pAz - tA.z)
            + sl1(pBx - tB.x) + sl1(pBy - tB.y) + sl1(pBz - tB.z);

    const int lane = tid & 63, wid = tid >> 6;
    #pragma unroll
    for (int off = 32; off; off >>= 1) s += __shfl_down(s, off, 64);
    if (lane == 0) sred[wid] = s;
    __syncthreads();
    if (tid == 0)
        partial[blockIdx.x] = (sred[0] + sred[1] + sred[2] + sred[3]) * W[bt];
}

// ---------------------------------------------------------------------------
// Finalize: one block. Sum 224 weighted partials -> out[0]; centroid loss
// from per-bt sums -> out[1]. Plain stores; no atomics, no memsets.
// ---------------------------------------------------------------------------
__global__ __launch_bounds__(256) void finalize_kernel(
    const float* __restrict__ sums, float* __restrict__ out)
{
    __shared__ float sred[4][2];
    const int tid = threadIdx.x;

    float lp = (tid < 224) ? sums[tid] : 0.0f;   // partial[] is at sums[0]

    float lc = 0.0f;
    if (tid < BT) {
        const float inv = 1.0f / Nc;
        #pragma unroll
        for (int c = 0; c < 3; ++c) {
            float pm = sums[WS_PSUM - WS_PARTIAL + tid * 3 + c] * inv;
            float tm = sums[WS_TSUM - WS_PARTIAL + tid * 3 + c] * inv;
            lc += sl1(pm - tm);
        }
    }

    const int lane = tid & 63, wid = tid >> 6;
    #pragma unroll
    for (int off = 32; off; off >>= 1) {
        lp += __shfl_down(lp, off, 64);
        lc += __shfl_down(lc, off, 64);
    }
    if (lane == 0) { sred[wid][0] = lp; sred[wid][1] = lc; }
    __syncthreads();
    if (tid == 0) {
        float tlp = sred[0][0] + sred[1][0] + sred[2][0] + sred[3][0];
        float tlc = sred[0][1] + sred[1][1] + sred[2][1] + sred[3][1];
        out[0] = tlp * (1.0f / (Nc * Dc)) * (1.0f / Bc);  // loss
        out[1] = tlc * (1.0f / (Bc * Dc));                // lossc
    }
}

extern "C" void kernel_launch(void* const* d_in, const int* in_sizes, int n_in,
                              void* d_out, int out_size, void* d_ws, size_t ws_size,
                              hipStream_t stream) {
    const float* X  = (const float*)d_in[0];  // X_v        [4,28,1024,3]
    const float* Tg = (const float*)d_in[1];  // target_X_v [4,28,1024,3]
    const float* W  = (const float*)d_in[2];  // weights    [4,28]
    float* out = (float*)d_out;               // {loss, lossc}

    float4* packed = (float4*)d_ws;                         // [112*1024] float4
    float*  sums   = (float*)d_ws + WS_PARTIAL;             // partial/psum/tsum

    prep_kernel<<<BT, 256, 0, stream>>>(X, Tg, packed, sums);
    chamfer_kernel<<<BT * 2, 256, 0, stream>>>(X, packed, W, sums /* partial at offset 0 */);
    finalize_kernel<<<1, 256, 0, stream>>>(sums, out);
}

// Round 6
// 88.720 us; speedup vs baseline: 1.1896x; 1.1896x over previous
//
#include <hip/hip_runtime.h>

// Problem constants (fixed by setup_inputs): B=4, T=28, N=1024, D=3
constexpr int Bc = 4;
constexpr int Tc = 28;
constexpr int Nc = 1024;
constexpr int Dc = 3;
constexpr int BT = Bc * Tc;       // 112
constexpr int QT = 256;           // targets per quarter

// ws layout (float units), ALL slots written before read -> no memsets:
//   bestv4 [BT*1024] float4 : per-pred best surrogate dist, component q = quarter q
//   besti4 [BT*1024] int4   : matching global target index
//   partial[224]            : per-(bt,ph) weighted sl1 sums (K2)
//   psum   [BT*2*3]         : pred-coord sums per (bt,ph)   (K1, th==0 blocks)
//   tsum   [BT*4*3]         : tgt-coord sums per (bt,th)    (K1, ph==0 blocks)
constexpr size_t WS_BESTV   = 0;                       // float4[BT*1024]
constexpr size_t WS_BESTI   = (size_t)BT * Nc * 4;     // int4 [BT*1024]
constexpr size_t WS_PARTIAL = WS_BESTI + (size_t)BT * Nc * 4;
constexpr size_t WS_PSUM    = WS_PARTIAL + 224;
constexpr size_t WS_TSUM    = WS_PSUM + BT * 2 * 3;

__device__ __forceinline__ float sl1(float d) {
    d = fabsf(d);
    return d < 1.0f ? 0.5f * d * d : d - 0.5f;
}

// ---------------------------------------------------------------------------
// K1: 896 blocks = 112 bt x 2 pred-halves x 4 target-quarters, 256 thr.
// 3.5 blocks/CU -> 14 waves/CU: TLP hides LDS latency (R3-R5 post-mortem:
// at 1 wave/SIMD every pipelining scheme stayed latency-bound ~100cyc/iter;
// occupancy is the knob that tracked VALUBusy). Each block scans a 4 KB
// LDS quarter (packed [x,y,z,||t||^2], broadcast ds_read_b128), 2 preds/thr,
// PF=8 register double-buffer on top.
// Surrogate v = tn - 2 p.t is argmin-equivalent to ||p-t||^2 per pred.
// ---------------------------------------------------------------------------
__global__ __launch_bounds__(256) void chamfer_quarter_kernel(
    const float* __restrict__ X, const float* __restrict__ Tg,
    float* __restrict__ bestv, int* __restrict__ besti,
    float* __restrict__ psum, float* __restrict__ tsum)
{
    __shared__ float4 sT4[QT];      // 4 KB packed quarter
    __shared__ float sred[4][3];

    const int bt  = blockIdx.x >> 3;
    const int ph  = (blockIdx.x >> 2) & 1;
    const int th  = blockIdx.x & 3;
    const int tid = threadIdx.x;

    // ---- this thread's 2 preds (issued before staging barrier) ----
    const float* xb = X + (size_t)bt * (Nc * Dc);
    const int n0 = ph * 512 + tid;
    const int n1 = n0 + 256;
    const float pAx = xb[n0 * 3 + 0], pAy = xb[n0 * 3 + 1], pAz = xb[n0 * 3 + 2];
    const float pBx = xb[n1 * 3 + 0], pBy = xb[n1 * 3 + 1], pBz = xb[n1 * 3 + 2];

    // ---- wave 0 stages + packs the 256-target quarter (4 targets/lane) ----
    if (tid < 64) {
        const float4* tg4 = (const float4*)(Tg + (size_t)bt * (Nc * Dc) + th * (QT * 3));
        const float4 r0 = tg4[3 * tid + 0];
        const float4 r1 = tg4[3 * tid + 1];
        const float4 r2 = tg4[3 * tid + 2];
        sT4[4 * tid + 0] = make_float4(r0.x, r0.y, r0.z, fmaf(r0.x, r0.x, fmaf(r0.y, r0.y, r0.z * r0.z)));
        sT4[4 * tid + 1] = make_float4(r0.w, r1.x, r1.y, fmaf(r0.w, r0.w, fmaf(r1.x, r1.x, r1.y * r1.y)));
        sT4[4 * tid + 2] = make_float4(r1.z, r1.w, r2.x, fmaf(r1.z, r1.z, fmaf(r1.w, r1.w, r2.x * r2.x)));
        sT4[4 * tid + 3] = make_float4(r2.y, r2.z, r2.w, fmaf(r2.y, r2.y, fmaf(r2.z, r2.z, r2.w * r2.w)));
        if (ph == 0) {  // target centroid partials ride along (once per (bt,th))
            float tx = r0.x + r0.w + r1.z + r2.y;
            float ty = r0.y + r1.x + r1.w + r2.z;
            float tz = r0.z + r1.y + r2.x + r2.w;
            #pragma unroll
            for (int off = 32; off; off >>= 1) {
                tx += __shfl_down(tx, off, 64);
                ty += __shfl_down(ty, off, 64);
                tz += __shfl_down(tz, off, 64);
            }
            if (tid == 0) {
                tsum[(bt * 4 + th) * 3 + 0] = tx;
                tsum[(bt * 4 + th) * 3 + 1] = ty;
                tsum[(bt * 4 + th) * 3 + 2] = tz;
            }
        }
    }
    __syncthreads();

    const float cA0 = -2.0f * pAx, cA1 = -2.0f * pAy, cA2 = -2.0f * pAz;
    const float cB0 = -2.0f * pBx, cB1 = -2.0f * pBy, cB2 = -2.0f * pBz;

    float bestA = 3.4e38f, bestB = 3.4e38f;
    int iA = 0, iB = 0;

    constexpr int PF = 8;
    float4 bufA[PF], bufB[PF];
    #pragma unroll
    for (int j = 0; j < PF; ++j) bufA[j] = sT4[j];

    for (int m0 = 0; m0 < QT; m0 += 2 * PF) {
        #pragma unroll
        for (int j = 0; j < PF; ++j) bufB[j] = sT4[m0 + PF + j];
        #pragma unroll
        for (int j = 0; j < PF; ++j) {
            const float4 t = bufA[j];
            const int m = m0 + j;
            float vA = fmaf(cA0, t.x, fmaf(cA1, t.y, fmaf(cA2, t.z, t.w)));
            float vB = fmaf(cB0, t.x, fmaf(cB1, t.y, fmaf(cB2, t.z, t.w)));
            bool ca = vA < bestA; bestA = ca ? vA : bestA; iA = ca ? m : iA;  // strict <: first min
            bool cb = vB < bestB; bestB = cb ? vB : bestB; iB = cb ? m : iB;
        }
        #pragma unroll
        for (int j = 0; j < PF; ++j) bufA[j] = sT4[(m0 + 2 * PF + j) & (QT - 1)];
        #pragma unroll
        for (int j = 0; j < PF; ++j) {
            const float4 t = bufB[j];
            const int m = m0 + PF + j;
            float vA = fmaf(cA0, t.x, fmaf(cA1, t.y, fmaf(cA2, t.z, t.w)));
            float vB = fmaf(cB0, t.x, fmaf(cB1, t.y, fmaf(cB2, t.z, t.w)));
            bool ca = vA < bestA; bestA = ca ? vA : bestA; iA = ca ? m : iA;
            bool cb = vB < bestB; bestB = cb ? vB : bestB; iB = cb ? m : iB;
        }
    }

    // ---- per-quarter results: component-sliced for K2's 16B loads ----
    const size_t base = (size_t)bt * Nc;
    bestv[(base + n0) * 4 + th] = bestA;
    bestv[(base + n1) * 4 + th] = bestB;
    besti[(base + n0) * 4 + th] = th * QT + iA;
    besti[(base + n1) * 4 + th] = th * QT + iB;

    // ---- pred centroid partials (once per (bt,ph): th==0 blocks) ----
    if (th == 0) {
        float sx = pAx + pBx, sy = pAy + pBy, sz = pAz + pBz;
        const int lane = tid & 63, wid = tid >> 6;
        #pragma unroll
        for (int off = 32; off; off >>= 1) {
            sx += __shfl_down(sx, off, 64);
            sy += __shfl_down(sy, off, 64);
            sz += __shfl_down(sz, off, 64);
        }
        if (lane == 0) { sred[wid][0] = sx; sred[wid][1] = sy; sred[wid][2] = sz; }
        __syncthreads();
        if (tid == 0) {
            #pragma unroll
            for (int k = 0; k < 3; ++k)
                psum[(bt * 2 + ph) * 3 + k] = sred[0][k] + sred[1][k] + sred[2][k] + sred[3][k];
        }
    }
}

// ---------------------------------------------------------------------------
// K2: 224 blocks = 112 bt x 2 pred-halves, 2 preds/thread. Combine the 4
// quarter-candidates (ascending q, strict < -> global first-occurrence
// tie-break), gather the winning target from Tg, smooth-L1, block-reduce.
// ---------------------------------------------------------------------------
__global__ __launch_bounds__(256) void gather_kernel(
    const float* __restrict__ X, const float* __restrict__ Tg,
    const float* __restrict__ W,
    const float4* __restrict__ bestv4, const int4* __restrict__ besti4,
    float* __restrict__ partial)
{
    __shared__ float sred[4];
    const int bt  = blockIdx.x >> 1;
    const int ph  = blockIdx.x & 1;
    const int tid = threadIdx.x;

    const float* xb = X  + (size_t)bt * (Nc * Dc);
    const float* tb = Tg + (size_t)bt * (Nc * Dc);
    const size_t base = (size_t)bt * Nc;

    float s = 0.0f;
    #pragma unroll
    for (int p = 0; p < 2; ++p) {
        const int n = ph * 512 + p * 256 + tid;
        const float4 bv = bestv4[base + n];
        const int4   bi = besti4[base + n];
        float best = bv.x; int idx = bi.x;
        if (bv.y < best) { best = bv.y; idx = bi.y; }
        if (bv.z < best) { best = bv.z; idx = bi.z; }
        if (bv.w < best) { best = bv.w; idx = bi.w; }
        const float px = xb[n * 3 + 0], py = xb[n * 3 + 1], pz = xb[n * 3 + 2];
        const float tx = tb[idx * 3 + 0], ty = tb[idx * 3 + 1], tz = tb[idx * 3 + 2];
        s += sl1(px - tx) + sl1(py - ty) + sl1(pz - tz);
    }

    const int lane = tid & 63, wid = tid >> 6;
    #pragma unroll
    for (int off = 32; off; off >>= 1) s += __shfl_down(s, off, 64);
    if (lane == 0) sred[wid] = s;
    __syncthreads();
    if (tid == 0)
        partial[blockIdx.x] = (sred[0] + sred[1] + sred[2] + sred[3]) * W[bt];
}

// ---------------------------------------------------------------------------
// K3: one block. partial[224] -> out[0]; centroid loss from psum/tsum -> out[1].
// ---------------------------------------------------------------------------
__global__ __launch_bounds__(256) void finalize_kernel(
    const float* __restrict__ ws, float* __restrict__ out)
{
    __shared__ float sred[4][2];
    const int tid = threadIdx.x;

    float lp = (tid < 224) ? ws[WS_PARTIAL + tid] : 0.0f;

    float lc = 0.0f;
    if (tid < BT) {
        const float inv = 1.0f / Nc;
        #pragma unroll
        for (int c = 0; c < 3; ++c) {
            float pm = (ws[WS_PSUM + (2 * tid) * 3 + c] + ws[WS_PSUM + (2 * tid + 1) * 3 + c]) * inv;
            float tm = (ws[WS_TSUM + (4 * tid) * 3 + c] + ws[WS_TSUM + (4 * tid + 1) * 3 + c]
                      + ws[WS_TSUM + (4 * tid + 2) * 3 + c] + ws[WS_TSUM + (4 * tid + 3) * 3 + c]) * inv;
            lc += sl1(pm - tm);
        }
    }

    const int lane = tid & 63, wid = tid >> 6;
    #pragma unroll
    for (int off = 32; off; off >>= 1) {
        lp += __shfl_down(lp, off, 64);
        lc += __shfl_down(lc, off, 64);
    }
    if (lane == 0) { sred[wid][0] = lp; sred[wid][1] = lc; }
    __syncthreads();
    if (tid == 0) {
        float tlp = sred[0][0] + sred[1][0] + sred[2][0] + sred[3][0];
        float tlc = sred[0][1] + sred[1][1] + sred[2][1] + sred[3][1];
        out[0] = tlp * (1.0f / (Nc * Dc)) * (1.0f / Bc);  // loss
        out[1] = tlc * (1.0f / (Bc * Dc));                // lossc
    }
}

extern "C" void kernel_launch(void* const* d_in, const int* in_sizes, int n_in,
                              void* d_out, int out_size, void* d_ws, size_t ws_size,
                              hipStream_t stream) {
    const float* X  = (const float*)d_in[0];  // X_v        [4,28,1024,3]
    const float* Tg = (const float*)d_in[1];  // target_X_v [4,28,1024,3]
    const float* W  = (const float*)d_in[2];  // weights    [4,28]
    float* out = (float*)d_out;               // {loss, lossc}
    float* ws  = (float*)d_ws;

    float* bestv = ws + WS_BESTV;
    int*   besti = (int*)(ws + WS_BESTI);
    float* psum  = ws + WS_PSUM;
    float* tsum  = ws + WS_TSUM;

    chamfer_quarter_kernel<<<BT * 8, 256, 0, stream>>>(X, Tg, bestv, besti, psum, tsum);
    gather_kernel<<<BT * 2, 256, 0, stream>>>(X, Tg, W,
        (const float4*)(ws + WS_BESTV), (const int4*)(ws + WS_BESTI), ws + WS_PARTIAL);
    finalize_kernel<<<1, 256, 0, stream>>>(ws, out);
}

// Round 7
// 85.615 us; speedup vs baseline: 1.2328x; 1.0363x over previous
//
#include <hip/hip_runtime.h>

// Problem constants (fixed by setup_inputs): B=4, T=28, N=1024, D=3
constexpr int Bc = 4;
constexpr int Tc = 28;
constexpr int Nc = 1024;
constexpr int Dc = 3;
constexpr int BT = Bc * Tc;       // 112
constexpr int QT = 256;           // targets per quarter
constexpr int NQ = 4;             // quarters

// ws layout (float units), ALL slots written before read -> no ws memsets:
//   bestvP [NQ][BT][256] float4 : per-(quarter,bt) best surrogate dist for pred-group tid
//   bestiP [NQ][BT][256] int4   : matching GLOBAL target indices
//   psum   [BT*3]               : pred-coord sums  (written by th==0 blocks)
//   tsum   [BT*NQ*3]            : tgt-coord sums per (bt,th)
constexpr size_t WS_BESTV = 0;                              // float4 units
constexpr size_t WS_BESTI = (size_t)NQ * BT * 256 * 4;      // float offset
constexpr size_t WS_PSUM  = WS_BESTI + (size_t)NQ * BT * 256 * 4;
constexpr size_t WS_TSUM  = WS_PSUM + BT * 3;

__device__ __forceinline__ float sl1(float d) {
    d = fabsf(d);
    return d < 1.0f ? 0.5f * d * d : d - 0.5f;
}

// ---------------------------------------------------------------------------
// K1: 448 blocks = 112 bt x 4 target-quarters, 256 thr, 4 preds/thread.
// R6 post-mortem: at P=2 the per-CU LDS issue pipe (1 broadcast b128/target
// per wave, ~12cyc) floors the kernel at ~18us regardless of occupancy.
// P=4 amortizes each broadcast over 24 VALU instr -> LDS 9us == VALU 9us,
// overlapped across 7 waves/CU. Thread t owns preds 4t..4t+3 (three coalesced
// float4 loads). Surrogate v = tn - 2 p.t is argmin-equivalent per pred;
// strict < keeps first minimum (jnp.argmin tie-break).
// ---------------------------------------------------------------------------
__global__ __launch_bounds__(256) void chamfer_kernel(
    const float* __restrict__ X, const float* __restrict__ Tg,
    float4* __restrict__ bestvP, int4* __restrict__ bestiP,
    float* __restrict__ psum, float* __restrict__ tsum)
{
    __shared__ float4 sT4[QT];      // 4 KB packed quarter [x,y,z,||t||^2]
    __shared__ float sred[4][3];

    const int bt  = blockIdx.x >> 2;
    const int th  = blockIdx.x & 3;
    const int tid = threadIdx.x;

    // ---- preds 4tid..4tid+3 (issued before the staging barrier) ----
    const float4* x4 = (const float4*)(X + (size_t)bt * (Nc * Dc));
    const float4 a0 = x4[3 * tid + 0];
    const float4 a1 = x4[3 * tid + 1];
    const float4 a2 = x4[3 * tid + 2];

    // ---- wave 0 stages + packs the 256-target quarter (4 targets/lane) ----
    if (tid < 64) {
        const float4* tg4 = (const float4*)(Tg + (size_t)bt * (Nc * Dc) + th * (QT * 3));
        const float4 r0 = tg4[3 * tid + 0];
        const float4 r1 = tg4[3 * tid + 1];
        const float4 r2 = tg4[3 * tid + 2];
        sT4[4 * tid + 0] = make_float4(r0.x, r0.y, r0.z, fmaf(r0.x, r0.x, fmaf(r0.y, r0.y, r0.z * r0.z)));
        sT4[4 * tid + 1] = make_float4(r0.w, r1.x, r1.y, fmaf(r0.w, r0.w, fmaf(r1.x, r1.x, r1.y * r1.y)));
        sT4[4 * tid + 2] = make_float4(r1.z, r1.w, r2.x, fmaf(r1.z, r1.z, fmaf(r1.w, r1.w, r2.x * r2.x)));
        sT4[4 * tid + 3] = make_float4(r2.y, r2.z, r2.w, fmaf(r2.y, r2.y, fmaf(r2.z, r2.z, r2.w * r2.w)));
        // target centroid partials ride along (once per (bt,th))
        float tx = r0.x + r0.w + r1.z + r2.y;
        float ty = r0.y + r1.x + r1.w + r2.z;
        float tz = r0.z + r1.y + r2.x + r2.w;
        #pragma unroll
        for (int off = 32; off; off >>= 1) {
            tx += __shfl_down(tx, off, 64);
            ty += __shfl_down(ty, off, 64);
            tz += __shfl_down(tz, off, 64);
        }
        if (tid == 0) {
            tsum[(bt * NQ + th) * 3 + 0] = tx;
            tsum[(bt * NQ + th) * 3 + 1] = ty;
            tsum[(bt * NQ + th) * 3 + 2] = tz;
        }
    }
    __syncthreads();

    // coefficient layout: pred k coords = (c0[k],c1[k],c2[k]) * -0.5
    const float c0[4] = {-2.f * a0.x, -2.f * a0.w, -2.f * a1.z, -2.f * a2.y};
    const float c1[4] = {-2.f * a0.y, -2.f * a1.x, -2.f * a1.w, -2.f * a2.z};
    const float c2[4] = {-2.f * a0.z, -2.f * a1.y, -2.f * a2.x, -2.f * a2.w};

    float best[4] = {3.4e38f, 3.4e38f, 3.4e38f, 3.4e38f};
    int idx[4] = {0, 0, 0, 0};

    constexpr int PF = 4;           // prefetch depth (register double-buffer)
    float4 bufA[PF], bufB[PF];
    #pragma unroll
    for (int j = 0; j < PF; ++j) bufA[j] = sT4[j];

    for (int m0 = 0; m0 < QT; m0 += 2 * PF) {
        #pragma unroll
        for (int j = 0; j < PF; ++j) bufB[j] = sT4[m0 + PF + j];
        #pragma unroll
        for (int j = 0; j < PF; ++j) {
            const float4 t = bufA[j];
            const int m = m0 + j;
            #pragma unroll
            for (int k = 0; k < 4; ++k) {
                float v = fmaf(c0[k], t.x, fmaf(c1[k], t.y, fmaf(c2[k], t.z, t.w)));
                bool c = v < best[k]; best[k] = c ? v : best[k]; idx[k] = c ? m : idx[k];
            }
        }
        #pragma unroll
        for (int j = 0; j < PF; ++j) bufA[j] = sT4[(m0 + 2 * PF + j) & (QT - 1)];
        #pragma unroll
        for (int j = 0; j < PF; ++j) {
            const float4 t = bufB[j];
            const int m = m0 + PF + j;
            #pragma unroll
            for (int k = 0; k < 4; ++k) {
                float v = fmaf(c0[k], t.x, fmaf(c1[k], t.y, fmaf(c2[k], t.z, t.w)));
                bool c = v < best[k]; best[k] = c ? v : best[k]; idx[k] = c ? m : idx[k];
            }
        }
    }

    // ---- planar per-quarter results: one coalesced float4/int4 per thread ----
    const size_t ob = ((size_t)th * BT + bt) * 256 + tid;
    bestvP[ob] = make_float4(best[0], best[1], best[2], best[3]);
    bestiP[ob] = make_int4(th * QT + idx[0], th * QT + idx[1],
                           th * QT + idx[2], th * QT + idx[3]);

    // ---- pred centroid partials (once per bt: th==0 blocks cover all 1024) ----
    if (th == 0) {
        float sx = a0.x + a0.w + a1.z + a2.y;
        float sy = a0.y + a1.x + a1.w + a2.z;
        float sz = a0.z + a1.y + a2.x + a2.w;
        const int lane = tid & 63, wid = tid >> 6;
        #pragma unroll
        for (int off = 32; off; off >>= 1) {
            sx += __shfl_down(sx, off, 64);
            sy += __shfl_down(sy, off, 64);
            sz += __shfl_down(sz, off, 64);
        }
        if (lane == 0) { sred[wid][0] = sx; sred[wid][1] = sy; sred[wid][2] = sz; }
        __syncthreads();
        if (tid == 0) {
            #pragma unroll
            for (int k = 0; k < 3; ++k)
                psum[bt * 3 + k] = sred[0][k] + sred[1][k] + sred[2][k] + sred[3][k];
        }
    }
}

// ---------------------------------------------------------------------------
// K2: 112 blocks (one per bt), 4 preds/thread (same group layout as K1).
// Combine 4 quarter-candidates (ascending q, strict < -> global first-
// occurrence tie-break), gather winning targets, smooth-L1, block-reduce,
// atomicAdd into out[0]. Block 0 also computes the centroid loss -> out[1].
// out is zeroed by an 8-byte memset node before this chain.
// ---------------------------------------------------------------------------
__global__ __launch_bounds__(256) void gather_finalize_kernel(
    const float* __restrict__ X, const float* __restrict__ Tg,
    const float* __restrict__ W,
    const float4* __restrict__ bestvP, const int4* __restrict__ bestiP,
    const float* __restrict__ psum, const float* __restrict__ tsum,
    float* __restrict__ out)
{
    __shared__ float sred[4];
    __shared__ float sred2[4];
    const int bt  = blockIdx.x;
    const int tid = threadIdx.x;
    const size_t rb = (size_t)bt * 256 + tid;

    float4 bv = bestvP[rb];          // quarter 0
    int4   bi = bestiP[rb];
    float best[4] = {bv.x, bv.y, bv.z, bv.w};
    int   idx[4]  = {bi.x, bi.y, bi.z, bi.w};
    #pragma unroll
    for (int q = 1; q < NQ; ++q) {
        const float4 v2 = bestvP[(size_t)q * BT * 256 + rb];
        const int4   i2 = bestiP[(size_t)q * BT * 256 + rb];
        if (v2.x < best[0]) { best[0] = v2.x; idx[0] = i2.x; }
        if (v2.y < best[1]) { best[1] = v2.y; idx[1] = i2.y; }
        if (v2.z < best[2]) { best[2] = v2.z; idx[2] = i2.z; }
        if (v2.w < best[3]) { best[3] = v2.w; idx[3] = i2.w; }
    }

    const float* tb = Tg + (size_t)bt * (Nc * Dc);
    const float4* x4 = (const float4*)(X + (size_t)bt * (Nc * Dc));
    const float4 a0 = x4[3 * tid + 0];
    const float4 a1 = x4[3 * tid + 1];
    const float4 a2 = x4[3 * tid + 2];
    const float px[4] = {a0.x, a0.w, a1.z, a2.y};
    const float py[4] = {a0.y, a1.x, a1.w, a2.z};
    const float pz[4] = {a0.z, a1.y, a2.x, a2.w};

    float s = 0.0f;
    #pragma unroll
    for (int k = 0; k < 4; ++k) {
        const float tx = tb[idx[k] * 3 + 0];
        const float ty = tb[idx[k] * 3 + 1];
        const float tz = tb[idx[k] * 3 + 2];
        s += sl1(px[k] - tx) + sl1(py[k] - ty) + sl1(pz[k] - tz);
    }

    const int lane = tid & 63, wid = tid >> 6;
    #pragma unroll
    for (int off = 32; off; off >>= 1) s += __shfl_down(s, off, 64);
    if (lane == 0) sred[wid] = s;
    __syncthreads();
    if (tid == 0) {
        float tot = sred[0] + sred[1] + sred[2] + sred[3];
        // loss contribution: w_bt * (sum / (N*D)) / B
        atomicAdd(out, tot * W[bt] * (1.0f / (Nc * Dc)) * (1.0f / Bc));
    }

    if (bt == 0) {
        float lc = 0.0f;
        if (tid < BT) {
            const float inv = 1.0f / Nc;
            #pragma unroll
            for (int c = 0; c < 3; ++c) {
                float pm = psum[tid * 3 + c] * inv;
                float tm = (tsum[(tid * NQ + 0) * 3 + c] + tsum[(tid * NQ + 1) * 3 + c]
                          + tsum[(tid * NQ + 2) * 3 + c] + tsum[(tid * NQ + 3) * 3 + c]) * inv;
                lc += sl1(pm - tm);
            }
        }
        float v = lc;
        #pragma unroll
        for (int off = 32; off; off >>= 1) v += __shfl_down(v, off, 64);
        if (lane == 0) sred2[wid] = v;
        __syncthreads();
        if (tid == 0) {
            float tlc = sred2[0] + sred2[1] + sred2[2] + sred2[3];
            atomicAdd(out + 1, tlc * (1.0f / (Bc * Dc)));   // lossc = sum / (B*3)
        }
    }
}

extern "C" void kernel_launch(void* const* d_in, const int* in_sizes, int n_in,
                              void* d_out, int out_size, void* d_ws, size_t ws_size,
                              hipStream_t stream) {
    const float* X  = (const float*)d_in[0];  // X_v        [4,28,1024,3]
    const float* Tg = (const float*)d_in[1];  // target_X_v [4,28,1024,3]
    const float* W  = (const float*)d_in[2];  // weights    [4,28]
    float* out = (float*)d_out;               // {loss, lossc}
    float* ws  = (float*)d_ws;

    float4* bestvP = (float4*)(ws + WS_BESTV);
    int4*   bestiP = (int4*)(ws + WS_BESTI);
    float*  psum   = ws + WS_PSUM;
    float*  tsum   = ws + WS_TSUM;

    hipMemsetAsync(out, 0, 2 * sizeof(float), stream);  // d_out is 0xAA-poisoned
    chamfer_kernel<<<BT * NQ, 256, 0, stream>>>(X, Tg, bestvP, bestiP, psum, tsum);
    gather_finalize_kernel<<<BT, 256, 0, stream>>>(X, Tg, W, bestvP, bestiP, psum, tsum, out);
}